// Round 1
// baseline (12383.449 us; speedup 1.0000x reference)
//
#include <hip/hip_runtime.h>
#include <hip/hip_bf16.h>
#include <math.h>

#define BB 8
#define TT 512
#define VV 50257
#define NN 768
#define HH 12
#define LL 12
#define MM (BB*TT)   // 4096 rows

// ---------------- embedding: x0 = wte[idx] + wpe ; h = x0 ----------------
__global__ void embed_kernel(const int* __restrict__ idx, const float* __restrict__ wte,
                             const float* __restrict__ wpe, float* __restrict__ x0,
                             float* __restrict__ h)
{
    int row = blockIdx.x;           // 0..4095  (= b*T + t)
    int t = row % TT;
    int tok = idx[row];
    const float* wt = wte + (size_t)tok * NN;
    const float* wp = wpe + (size_t)t * NN;
    float* px = x0 + (size_t)row * NN;
    float* ph = h  + (size_t)row * NN;
    for (int c = threadIdx.x; c < NN; c += blockDim.x) {
        float v = wt[c] + wp[c];
        px[c] = v; ph[c] = v;
    }
}

// ---------------- layernorm; ADD3 variant fuses hin = h + x0 + se ----------------
template<bool ADD3>
__global__ __launch_bounds__(256) void ln_kernel(
    const float* __restrict__ src, const float* __restrict__ x0,
    const float* __restrict__ se, const float* __restrict__ w,
    float* __restrict__ hin_out, float* __restrict__ out)
{
    int row = blockIdx.x;
    size_t base = (size_t)row * NN;
    int tid = threadIdx.x;
    float v[3];
    float s = 0.f, ss = 0.f;
#pragma unroll
    for (int i = 0; i < 3; ++i) {
        int c = tid + i * 256;
        float val = src[base + c];
        if (ADD3) { val += x0[base + c] + se[c]; hin_out[base + c] = val; }
        v[i] = val; s += val; ss += val * val;
    }
#pragma unroll
    for (int off = 32; off; off >>= 1) { s += __shfl_xor(s, off); ss += __shfl_xor(ss, off); }
    __shared__ float rs[4], rss[4], bc[2];
    int wid = tid >> 6, lane = tid & 63;
    if (lane == 0) { rs[wid] = s; rss[wid] = ss; }
    __syncthreads();
    if (tid == 0) {
        float S  = rs[0] + rs[1] + rs[2] + rs[3];
        float SS = rss[0] + rss[1] + rss[2] + rss[3];
        float mu = S / (float)NN;
        float var = SS / (float)NN - mu * mu;
        bc[0] = mu; bc[1] = rsqrtf(var + 1e-5f);
    }
    __syncthreads();
    float mu = bc[0], rsig = bc[1];
#pragma unroll
    for (int i = 0; i < 3; ++i) {
        int c = tid + i * 256;
        out[base + c] = (v[i] - mu) * rsig * w[c];
    }
}

// ---------------- fp32 tiled GEMM: C[M,N] = A[M,K] @ B[K,N] (+epilogue) ----------------
// EPI: 0 = none, 1 = exact GELU, 2 = residual add (C = res + A@B)
template<int EPI>
__global__ __launch_bounds__(256) void gemm_kernel(
    const float* __restrict__ A, const float* __restrict__ Bw,
    const float* __restrict__ res, float* __restrict__ C,
    int N, int K)
{
    __shared__ float As[16][64];
    __shared__ float Bs[16][64];
    int tid = threadIdx.x;
    int tx = tid & 15, ty = tid >> 4;
    int row0 = blockIdx.y * 64;
    int col0 = blockIdx.x * 64;
    float acc[4][4] = {};

    for (int k0 = 0; k0 < K; k0 += 16) {
        // A tile 64x16 -> transposed into As[k][m]
        {
            int m  = tid >> 2;
            int kk = (tid & 3) * 4;
            const float* srcp = A + (size_t)(row0 + m) * K + k0 + kk;
            float4 av = *(const float4*)srcp;
            As[kk + 0][m] = av.x; As[kk + 1][m] = av.y;
            As[kk + 2][m] = av.z; As[kk + 3][m] = av.w;
        }
        // B tile 16x64
        {
            int r = tid >> 4;
            int c = (tid & 15) * 4;
            const float* srcp = Bw + (size_t)(k0 + r) * N + col0 + c;
            *(float4*)&Bs[r][c] = *(const float4*)srcp;
        }
        __syncthreads();
#pragma unroll
        for (int kk = 0; kk < 16; ++kk) {
            float4 a = *(const float4*)&As[kk][ty * 4];
            float4 b = *(const float4*)&Bs[kk][tx * 4];
            acc[0][0] += a.x * b.x; acc[0][1] += a.x * b.y; acc[0][2] += a.x * b.z; acc[0][3] += a.x * b.w;
            acc[1][0] += a.y * b.x; acc[1][1] += a.y * b.y; acc[1][2] += a.y * b.z; acc[1][3] += a.y * b.w;
            acc[2][0] += a.z * b.x; acc[2][1] += a.z * b.y; acc[2][2] += a.z * b.z; acc[2][3] += a.z * b.w;
            acc[3][0] += a.w * b.x; acc[3][1] += a.w * b.y; acc[3][2] += a.w * b.z; acc[3][3] += a.w * b.w;
        }
        __syncthreads();
    }
#pragma unroll
    for (int i = 0; i < 4; ++i) {
        int row = row0 + ty * 4 + i;
#pragma unroll
        for (int j = 0; j < 4; ++j) {
            int col = col0 + tx * 4 + j;
            float vv = acc[i][j];
            if (EPI == 1) vv = 0.5f * vv * (1.0f + erff(vv * 0.70710678118654752f));
            if (EPI == 2) vv += res[(size_t)row * N + col];
            C[(size_t)row * N + col] = vv;
        }
    }
}

// ---------------- attention: y = softmax(QK^T/8, causal) V ----------------
// grid (T/4, H, B); 256 threads = 4 waves; wave w handles q-row t = qt*4+w
__global__ __launch_bounds__(256) void attn_kernel(const float* __restrict__ qkv,
                                                   float* __restrict__ y)
{
    int qt = blockIdx.x, h = blockIdx.y, b = blockIdx.z;
    int w = threadIdx.x >> 6, lane = threadIdx.x & 63;
    int t = qt * 4 + w;

    __shared__ float qs[4][64];
    __shared__ float kv[64][68];
    __shared__ float sc[4][512];

    { // load 4 q rows
        int r = threadIdx.x >> 6, d = threadIdx.x & 63;
        qs[r][d] = qkv[(size_t)(b * TT + qt * 4 + r) * 2304 + h * 64 + d];
    }
    int tmax = qt * 4 + 3;
    int ntile = tmax / 64 + 1;
    const float scale = 0.125f;

    for (int kt = 0; kt < ntile; ++kt) {
        __syncthreads();
        { // load K tile 64x64
            int r = threadIdx.x >> 2;
            int c0 = (threadIdx.x & 3) * 16;
            const float* srcp = &qkv[(size_t)(b * TT + kt * 64 + r) * 2304 + 768 + h * 64 + c0];
#pragma unroll
            for (int q4 = 0; q4 < 4; ++q4)
                *(float4*)&kv[r][c0 + q4 * 4] = ((const float4*)srcp)[q4];
        }
        __syncthreads();
        int j = kt * 64 + lane;
        if (j <= t) {
            float s = 0.f;
#pragma unroll
            for (int d0 = 0; d0 < 64; d0 += 4) {
                float4 qv = *(const float4*)&qs[w][d0];
                s += qv.x * kv[lane][d0] + qv.y * kv[lane][d0 + 1]
                   + qv.z * kv[lane][d0 + 2] + qv.w * kv[lane][d0 + 3];
            }
            sc[w][j] = s * scale;
        }
    }
    // per-wave softmax over j<=t
    float m = -1e30f;
    for (int j = lane; j <= t; j += 64) m = fmaxf(m, sc[w][j]);
#pragma unroll
    for (int off = 32; off; off >>= 1) m = fmaxf(m, __shfl_xor(m, off));
    float ssum = 0.f;
    for (int j = lane; j <= t; j += 64) { float p = expf(sc[w][j] - m); sc[w][j] = p; ssum += p; }
#pragma unroll
    for (int off = 32; off; off >>= 1) ssum += __shfl_xor(ssum, off);
    float inv = 1.0f / ssum;

    float acc = 0.f;
    for (int vt = 0; vt < ntile; ++vt) {
        __syncthreads();
        { // load V tile 64x64
            int r = threadIdx.x >> 2;
            int c0 = (threadIdx.x & 3) * 16;
            const float* srcp = &qkv[(size_t)(b * TT + vt * 64 + r) * 2304 + 1536 + h * 64 + c0];
#pragma unroll
            for (int q4 = 0; q4 < 4; ++q4)
                *(float4*)&kv[r][c0 + q4 * 4] = ((const float4*)srcp)[q4];
        }
        __syncthreads();
        if (t >= vt * 64) {
            int jend = min(63, t - vt * 64);
            for (int jl = 0; jl <= jend; ++jl)
                acc += sc[w][vt * 64 + jl] * kv[jl][lane];
        }
    }
    y[(size_t)(b * TT + t) * NN + h * 64 + lane] = acc * inv;
}

// ---------------- logits: out[b,v] = dot(hf[b,T-1,:], wte[v,:]) ----------------
__global__ __launch_bounds__(256) void logits_kernel(const float* __restrict__ hf,
                                                     const float* __restrict__ wte,
                                                     float* __restrict__ out)
{
    __shared__ float hl[BB][NN];
    for (int i = threadIdx.x; i < BB * NN; i += 256) {
        int b = i / NN, d = i % NN;
        hl[b][d] = hf[(size_t)(b * TT + TT - 1) * NN + d];
    }
    __syncthreads();
    int w = threadIdx.x >> 6, lane = threadIdx.x & 63;
    int v = blockIdx.x * 4 + w;
    if (v >= VV) return;
    float acc[BB] = {};
    const float* wr = wte + (size_t)v * NN;
    for (int d = lane; d < NN; d += 64) {
        float wv = wr[d];
#pragma unroll
        for (int b = 0; b < BB; ++b) acc[b] += wv * hl[b][d];
    }
#pragma unroll
    for (int off = 32; off; off >>= 1)
#pragma unroll
        for (int b = 0; b < BB; ++b) acc[b] += __shfl_xor(acc[b], off);
    if (lane == 0)
#pragma unroll
        for (int b = 0; b < BB; ++b) out[(size_t)b * VV + v] = acc[b];
}

extern "C" void kernel_launch(void* const* d_in, const int* in_sizes, int n_in,
                              void* d_out, int out_size, void* d_ws, size_t ws_size,
                              hipStream_t stream) {
    const int*   idx       = (const int*)d_in[0];
    const float* wte       = (const float*)d_in[1];
    const float* wpe       = (const float*)d_in[2];
    const float* step_emb  = (const float*)d_in[3];
    const float* ln1_w     = (const float*)d_in[4];
    const float* ln2_w     = (const float*)d_in[5];
    const float* lnf_w     = (const float*)d_in[6];
    const float* c_attn    = (const float*)d_in[7];
    const float* attn_proj = (const float*)d_in[8];
    const float* c_fc      = (const float*)d_in[9];
    const float* mlp_proj  = (const float*)d_in[10];
    float* out = (float*)d_out;

    float* ws = (float*)d_ws;
    const size_t RC = (size_t)MM * NN;     // 3,145,728 floats
    float* x0  = ws;
    float* h   = ws + RC;
    float* hin = ws + 2 * RC;
    float* lnb = ws + 3 * RC;
    float* big = ws + 4 * RC;              // 4096*3072 floats (qkv / mlp-mid)

    embed_kernel<<<MM, 256, 0, stream>>>(idx, wte, wpe, x0, h);

    for (int l = 0; l < LL; ++l) {
        // hin = h + x0 + se[l]; lnb = LN(hin, ln1_w)
        ln_kernel<true><<<MM, 256, 0, stream>>>(h, x0, step_emb + l * NN, ln1_w, hin, lnb);
        // qkv = lnb @ c_attn  [4096 x 2304]
        gemm_kernel<0><<<dim3(3 * NN / 64, MM / 64), 256, 0, stream>>>(lnb, c_attn, nullptr, big, 3 * NN, NN);
        // y = attention(qkv) -> lnb
        attn_kernel<<<dim3(TT / 4, HH, BB), 256, 0, stream>>>(big, lnb);
        // hin = hin + y @ attn_proj  (in-place residual)
        gemm_kernel<2><<<dim3(NN / 64, MM / 64), 256, 0, stream>>>(lnb, attn_proj, hin, hin, NN, NN);
        // lnb = LN(hin, ln2_w)
        ln_kernel<false><<<MM, 256, 0, stream>>>(hin, nullptr, nullptr, ln2_w, nullptr, lnb);
        // big = gelu(lnb @ c_fc)  [4096 x 3072]
        gemm_kernel<1><<<dim3(4 * NN / 64, MM / 64), 256, 0, stream>>>(lnb, c_fc, nullptr, big, 4 * NN, NN);
        // h = hin + big @ mlp_proj
        gemm_kernel<2><<<dim3(NN / 64, MM / 64), 256, 0, stream>>>(big, mlp_proj, hin, h, NN, 4 * NN);
    }

    // final LN + last-position logits
    ln_kernel<false><<<MM, 256, 0, stream>>>(h, nullptr, nullptr, lnf_w, nullptr, lnb);
    logits_kernel<<<(VV + 3) / 4, 256, 0, stream>>>(lnb, wte, out);
}

// Round 2
// 4766.984 us; speedup vs baseline: 2.5978x; 2.5978x over previous
//
#include <hip/hip_runtime.h>
#include <hip/hip_bf16.h>
#include <math.h>

#define BB 8
#define TT 512
#define VV 50257
#define NN 768
#define HH 12
#define LL 12
#define MM (BB*TT)   // 4096 rows

typedef short bf16x8 __attribute__((ext_vector_type(8)));
typedef float f32x4 __attribute__((ext_vector_type(4)));
typedef unsigned short us8 __attribute__((ext_vector_type(8)));

__device__ __forceinline__ float bf2f(unsigned short u) {
    union { unsigned int i; float f; } x; x.i = ((unsigned int)u) << 16; return x.f;
}
__device__ __forceinline__ unsigned short f2bf(float f) {
    union { __hip_bfloat16 h; unsigned short u; } c; c.h = __float2bfloat16(f); return c.u;
}

// ---------------- embedding: x0 = wte[idx] + wpe ; h = x0 ----------------
__global__ void embed_kernel(const int* __restrict__ idx, const float* __restrict__ wte,
                             const float* __restrict__ wpe, float* __restrict__ x0,
                             float* __restrict__ h)
{
    int row = blockIdx.x;
    int t = row % TT;
    int tok = idx[row];
    const float* wt = wte + (size_t)tok * NN;
    const float* wp = wpe + (size_t)t * NN;
    float* px = x0 + (size_t)row * NN;
    float* ph = h  + (size_t)row * NN;
    for (int c = threadIdx.x; c < NN; c += blockDim.x) {
        float v = wt[c] + wp[c];
        px[c] = v; ph[c] = v;
    }
}

// ---------------- weight convert+transpose: W[K][Nc] fp32 -> Wt[Nc][K] bf16 ----------------
__global__ __launch_bounds__(256) void wconv_kernel(const float* __restrict__ W,
                                                    unsigned short* __restrict__ Wt,
                                                    int K, int Nc)
{
    __shared__ float tile[32][33];
    int n0 = blockIdx.x * 32, k0 = blockIdx.y * 32;
    int tid = threadIdx.x;
    int r = tid >> 3, c4 = (tid & 7) * 4;
    float4 v = *(const float4*)&W[(size_t)(k0 + r) * Nc + n0 + c4];
    tile[r][c4 + 0] = v.x; tile[r][c4 + 1] = v.y;
    tile[r][c4 + 2] = v.z; tile[r][c4 + 3] = v.w;
    __syncthreads();
    ushort4 o;
    o.x = f2bf(tile[c4 + 0][r]); o.y = f2bf(tile[c4 + 1][r]);
    o.z = f2bf(tile[c4 + 2][r]); o.w = f2bf(tile[c4 + 3][r]);
    *(ushort4*)&Wt[(size_t)(n0 + r) * K + k0 + c4] = o;
}

// ---------------- layernorm; ADD3 fuses hin = h + x0 + se; OutT = bf16(ushort) or float ----------------
template<bool ADD3, typename OutT>
__global__ __launch_bounds__(256) void ln_kernel(
    const float* __restrict__ src, const float* __restrict__ x0,
    const float* __restrict__ se, const float* __restrict__ w,
    float* __restrict__ hin_out, OutT* __restrict__ out)
{
    int row = blockIdx.x;
    size_t base = (size_t)row * NN;
    int tid = threadIdx.x;
    float v[3];
    float s = 0.f, ss = 0.f;
#pragma unroll
    for (int i = 0; i < 3; ++i) {
        int c = tid + i * 256;
        float val = src[base + c];
        if (ADD3) { val += x0[base + c] + se[c]; hin_out[base + c] = val; }
        v[i] = val; s += val; ss += val * val;
    }
#pragma unroll
    for (int off = 32; off; off >>= 1) { s += __shfl_xor(s, off); ss += __shfl_xor(ss, off); }
    __shared__ float rs[4], rss[4], bc[2];
    int wid = tid >> 6, lane = tid & 63;
    if (lane == 0) { rs[wid] = s; rss[wid] = ss; }
    __syncthreads();
    if (tid == 0) {
        float S  = rs[0] + rs[1] + rs[2] + rs[3];
        float SS = rss[0] + rss[1] + rss[2] + rss[3];
        float mu = S / (float)NN;
        float var = SS / (float)NN - mu * mu;
        bc[0] = mu; bc[1] = rsqrtf(var + 1e-5f);
    }
    __syncthreads();
    float mu = bc[0], rsig = bc[1];
#pragma unroll
    for (int i = 0; i < 3; ++i) {
        int c = tid + i * 256;
        float o = (v[i] - mu) * rsig * w[c];
        if constexpr (sizeof(OutT) == 2) out[base + c] = (OutT)f2bf(o);
        else out[base + c] = o;
    }
}

// ---------------- bf16 MFMA GEMM: C[M,N] = A[M,K] @ Bt[N,K]^T (+epilogue) ----------------
// m97 structure: 128x128 tile, BK=32, 4 waves 2x2, global_load_lds width 16.
// EPI: 0 = none, 1 = exact GELU, 2 = residual add
template<int EPI, typename OutT>
__global__ __launch_bounds__(256) void mgemm(
    const unsigned short* __restrict__ A, const unsigned short* __restrict__ Bt,
    const float* __restrict__ res, OutT* __restrict__ C, int N, int K)
{
    __shared__ unsigned short Asb[128 * 32];
    __shared__ unsigned short Bsb[128 * 32];
    int tid = threadIdx.x;
    int row0 = blockIdx.y * 128, col0 = blockIdx.x * 128;
    const unsigned short* Ap = A + (size_t)row0 * K;
    const unsigned short* Bp = Bt + (size_t)col0 * K;
    int lane = tid & 63, wid = tid >> 6;
    int wr = wid >> 1, wc = wid & 1;
    int fr = lane & 15, fq = lane >> 4;

    f32x4 acc[4][4];
#pragma unroll
    for (int m = 0; m < 4; ++m)
#pragma unroll
        for (int n = 0; n < 4; ++n)
#pragma unroll
            for (int r = 0; r < 4; ++r) acc[m][n][r] = 0.f;

    int ldso = (tid & 192) * 8;   // wave-uniform LDS base (elems); HW adds lane*16B

    for (int k0 = 0; k0 < K; k0 += 32) {
        __syncthreads();
#pragma unroll
        for (int i = 0; i < 2; ++i) {
            int c = i * 256 + tid;              // chunk id: row = c>>2, 16B piece = c&3
            __builtin_amdgcn_global_load_lds(
                (const __attribute__((address_space(1))) void*)(Ap + (size_t)(c >> 2) * K + k0 + (c & 3) * 8),
                (__attribute__((address_space(3))) void*)(Asb + i * 2048 + ldso), 16, 0, 0);
            __builtin_amdgcn_global_load_lds(
                (const __attribute__((address_space(1))) void*)(Bp + (size_t)(c >> 2) * K + k0 + (c & 3) * 8),
                (__attribute__((address_space(3))) void*)(Bsb + i * 2048 + ldso), 16, 0, 0);
        }
        __syncthreads();
        const unsigned short* Ab = Asb + (wr * 64 + fr) * 32 + fq * 8;
        const unsigned short* Bb = Bsb + (wc * 64 + fr) * 32 + fq * 8;
        bf16x8 af[4], bfr[4];
#pragma unroll
        for (int m = 0; m < 4; ++m) af[m] = *(const bf16x8*)(Ab + m * 512);
#pragma unroll
        for (int n = 0; n < 4; ++n) bfr[n] = *(const bf16x8*)(Bb + n * 512);
#pragma unroll
        for (int m = 0; m < 4; ++m)
#pragma unroll
            for (int n = 0; n < 4; ++n)
                acc[m][n] = __builtin_amdgcn_mfma_f32_16x16x32_bf16(af[m], bfr[n], acc[m][n], 0, 0, 0);
    }

#pragma unroll
    for (int m = 0; m < 4; ++m) {
#pragma unroll
        for (int n = 0; n < 4; ++n) {
            int col = col0 + wc * 64 + n * 16 + fr;
#pragma unroll
            for (int r = 0; r < 4; ++r) {
                int row = row0 + wr * 64 + m * 16 + fq * 4 + r;
                float v = acc[m][n][r];
                if (EPI == 1) v = 0.5f * v * (1.0f + erff(v * 0.70710678118654752f));
                if (EPI == 2) v += res[(size_t)row * N + col];
                if constexpr (sizeof(OutT) == 2) C[(size_t)row * N + col] = (OutT)f2bf(v);
                else C[(size_t)row * N + col] = v;
            }
        }
    }
}

// ---------------- attention: y = softmax(QK^T/8, causal) V ; bf16 qkv in, bf16 y out ----------------
__global__ __launch_bounds__(256) void attn_kernel(const unsigned short* __restrict__ qkv,
                                                   unsigned short* __restrict__ y)
{
    int qt = blockIdx.x, h = blockIdx.y, b = blockIdx.z;
    int w = threadIdx.x >> 6, lane = threadIdx.x & 63;
    int t = qt * 4 + w;

    __shared__ float qs[4][64];
    __shared__ float kv[64][68];
    __shared__ float sc[4][512];

    { // load 4 q rows
        int r = threadIdx.x >> 6, d = threadIdx.x & 63;
        qs[r][d] = bf2f(qkv[(size_t)(b * TT + qt * 4 + r) * 2304 + h * 64 + d]);
    }
    int tmax = qt * 4 + 3;
    int ntile = tmax / 64 + 1;
    const float scale = 0.125f;

    for (int kt = 0; kt < ntile; ++kt) {
        __syncthreads();
        { // load K tile 64x64 (bf16 -> fp32)
            int r = threadIdx.x >> 2;
            int c0 = (threadIdx.x & 3) * 16;
            const us8* srcp = (const us8*)&qkv[(size_t)(b * TT + kt * 64 + r) * 2304 + 768 + h * 64 + c0];
            us8 v0 = srcp[0], v1 = srcp[1];
#pragma unroll
            for (int j = 0; j < 8; ++j) { kv[r][c0 + j] = bf2f(v0[j]); kv[r][c0 + 8 + j] = bf2f(v1[j]); }
        }
        __syncthreads();
        int j = kt * 64 + lane;
        if (j <= t) {
            float s = 0.f;
#pragma unroll
            for (int d0 = 0; d0 < 64; d0 += 4) {
                float4 qv = *(const float4*)&qs[w][d0];
                s += qv.x * kv[lane][d0] + qv.y * kv[lane][d0 + 1]
                   + qv.z * kv[lane][d0 + 2] + qv.w * kv[lane][d0 + 3];
            }
            sc[w][j] = s * scale;
        }
    }
    float m = -1e30f;
    for (int j = lane; j <= t; j += 64) m = fmaxf(m, sc[w][j]);
#pragma unroll
    for (int off = 32; off; off >>= 1) m = fmaxf(m, __shfl_xor(m, off));
    float ssum = 0.f;
    for (int j = lane; j <= t; j += 64) { float p = expf(sc[w][j] - m); sc[w][j] = p; ssum += p; }
#pragma unroll
    for (int off = 32; off; off >>= 1) ssum += __shfl_xor(ssum, off);
    float inv = 1.0f / ssum;

    float acc = 0.f;
    for (int vt = 0; vt < ntile; ++vt) {
        __syncthreads();
        { // load V tile 64x64 (bf16 -> fp32)
            int r = threadIdx.x >> 2;
            int c0 = (threadIdx.x & 3) * 16;
            const us8* srcp = (const us8*)&qkv[(size_t)(b * TT + vt * 64 + r) * 2304 + 1536 + h * 64 + c0];
            us8 v0 = srcp[0], v1 = srcp[1];
#pragma unroll
            for (int j = 0; j < 8; ++j) { kv[r][c0 + j] = bf2f(v0[j]); kv[r][c0 + 8 + j] = bf2f(v1[j]); }
        }
        __syncthreads();
        if (t >= vt * 64) {
            int jend = min(63, t - vt * 64);
            for (int jl = 0; jl <= jend; ++jl)
                acc += sc[w][vt * 64 + jl] * kv[jl][lane];
        }
    }
    y[(size_t)(b * TT + t) * NN + h * 64 + lane] = f2bf(acc * inv);
}

// ---------------- logits: out[b,v] = dot(hf[b,T-1,:], wte[v,:]) ----------------
__global__ __launch_bounds__(256) void logits_kernel(const float* __restrict__ hf,
                                                     const float* __restrict__ wte,
                                                     float* __restrict__ out)
{
    __shared__ float hl[BB][NN];
    for (int i = threadIdx.x; i < BB * NN; i += 256) {
        int b = i / NN, d = i % NN;
        hl[b][d] = hf[(size_t)(b * TT + TT - 1) * NN + d];
    }
    __syncthreads();
    int w = threadIdx.x >> 6, lane = threadIdx.x & 63;
    int v = blockIdx.x * 4 + w;
    if (v >= VV) return;
    float acc[BB] = {};
    const float* wr = wte + (size_t)v * NN;
    for (int d = lane; d < NN; d += 64) {
        float wv = wr[d];
#pragma unroll
        for (int b = 0; b < BB; ++b) acc[b] += wv * hl[b][d];
    }
#pragma unroll
    for (int off = 32; off; off >>= 1)
#pragma unroll
        for (int b = 0; b < BB; ++b) acc[b] += __shfl_xor(acc[b], off);
    if (lane == 0)
#pragma unroll
        for (int b = 0; b < BB; ++b) out[(size_t)b * VV + v] = acc[b];
}

extern "C" void kernel_launch(void* const* d_in, const int* in_sizes, int n_in,
                              void* d_out, int out_size, void* d_ws, size_t ws_size,
                              hipStream_t stream) {
    const int*   idx       = (const int*)d_in[0];
    const float* wte       = (const float*)d_in[1];
    const float* wpe       = (const float*)d_in[2];
    const float* step_emb  = (const float*)d_in[3];
    const float* ln1_w     = (const float*)d_in[4];
    const float* ln2_w     = (const float*)d_in[5];
    const float* lnf_w     = (const float*)d_in[6];
    const float* c_attn    = (const float*)d_in[7];
    const float* attn_proj = (const float*)d_in[8];
    const float* c_fc      = (const float*)d_in[9];
    const float* mlp_proj  = (const float*)d_in[10];
    float* out = (float*)d_out;

    float* ws = (float*)d_ws;
    const size_t RC = (size_t)MM * NN;          // 3,145,728
    float* x0  = ws;
    float* h   = ws + RC;
    float* hin = ws + 2 * RC;
    unsigned short* big = (unsigned short*)(ws + 3 * RC);          // MM x 3072 bf16 (qkv / gelu-out share)
    unsigned short* lnb = (unsigned short*)(ws + 3 * RC + (size_t)MM * 3072 / 2);
    unsigned short* yb       = lnb + RC;
    unsigned short* cattn_bt = yb + RC;                            // [2304][768]
    unsigned short* aproj_bt = cattn_bt + (size_t)2304 * 768;      // [768][768]
    unsigned short* cfc_bt   = aproj_bt + (size_t)768 * 768;       // [3072][768]
    unsigned short* mproj_bt = cfc_bt + (size_t)768 * 3072;        // [768][3072]

    // one-time (per launch) weight convert + transpose to bf16 [N][K]
    wconv_kernel<<<dim3(2304 / 32, 768 / 32), 256, 0, stream>>>(c_attn, cattn_bt, 768, 2304);
    wconv_kernel<<<dim3(768 / 32, 768 / 32), 256, 0, stream>>>(attn_proj, aproj_bt, 768, 768);
    wconv_kernel<<<dim3(3072 / 32, 768 / 32), 256, 0, stream>>>(c_fc, cfc_bt, 768, 3072);
    wconv_kernel<<<dim3(768 / 32, 3072 / 32), 256, 0, stream>>>(mlp_proj, mproj_bt, 3072, 768);

    embed_kernel<<<MM, 256, 0, stream>>>(idx, wte, wpe, x0, h);

    for (int l = 0; l < LL; ++l) {
        ln_kernel<true, unsigned short><<<MM, 256, 0, stream>>>(h, x0, step_emb + l * NN, ln1_w, hin, lnb);
        mgemm<0, unsigned short><<<dim3(2304 / 128, MM / 128), 256, 0, stream>>>(lnb, cattn_bt, nullptr, big, 2304, 768);
        attn_kernel<<<dim3(TT / 4, HH, BB), 256, 0, stream>>>(big, yb);
        mgemm<2, float><<<dim3(768 / 128, MM / 128), 256, 0, stream>>>(yb, aproj_bt, hin, hin, 768, 768);
        ln_kernel<false, unsigned short><<<MM, 256, 0, stream>>>(hin, nullptr, nullptr, ln2_w, nullptr, lnb);
        mgemm<1, unsigned short><<<dim3(3072 / 128, MM / 128), 256, 0, stream>>>(lnb, cfc_bt, nullptr, big, 3072, 768);
        mgemm<2, float><<<dim3(768 / 128, MM / 128), 256, 0, stream>>>(big, mproj_bt, hin, h, 768, 3072);
    }

    ln_kernel<false, float><<<MM, 256, 0, stream>>>(h, nullptr, nullptr, lnf_w, nullptr, x0);
    logits_kernel<<<(VV + 3) / 4, 256, 0, stream>>>(x0, wte, out);
}

// Round 3
// 2584.317 us; speedup vs baseline: 4.7918x; 1.8446x over previous
//
#include <hip/hip_runtime.h>
#include <hip/hip_bf16.h>
#include <math.h>

#define BB 8
#define TT 512
#define VV 50257
#define NN 768
#define HH 12
#define LL 12
#define MM (BB*TT)   // 4096 rows

typedef short bf16x8 __attribute__((ext_vector_type(8)));
typedef float f32x4 __attribute__((ext_vector_type(4)));
typedef unsigned short us8 __attribute__((ext_vector_type(8)));

__device__ __forceinline__ float bf2f(unsigned short u) {
    union { unsigned int i; float f; } x; x.i = ((unsigned int)u) << 16; return x.f;
}
__device__ __forceinline__ unsigned short f2bf(float f) {
    union { __hip_bfloat16 h; unsigned short u; } c; c.h = __float2bfloat16(f); return c.u;
}

// ---------------- embedding: x0 = wte[idx] + wpe ; h = x0 ----------------
__global__ void embed_kernel(const int* __restrict__ idx, const float* __restrict__ wte,
                             const float* __restrict__ wpe, float* __restrict__ x0,
                             float* __restrict__ h)
{
    int row = blockIdx.x;
    int t = row % TT;
    int tok = idx[row];
    const float* wt = wte + (size_t)tok * NN;
    const float* wp = wpe + (size_t)t * NN;
    float* px = x0 + (size_t)row * NN;
    float* ph = h  + (size_t)row * NN;
    for (int c = threadIdx.x; c < NN; c += blockDim.x) {
        float v = wt[c] + wp[c];
        px[c] = v; ph[c] = v;
    }
}

// ---------------- weight convert+transpose: W[K][Nc] fp32 -> Wt[Nc][K] bf16 ----------------
__global__ __launch_bounds__(256) void wconv_kernel(const float* __restrict__ W,
                                                    unsigned short* __restrict__ Wt,
                                                    int K, int Nc)
{
    __shared__ float tile[32][33];
    int n0 = blockIdx.x * 32, k0 = blockIdx.y * 32;
    int tid = threadIdx.x;
    int r = tid >> 3, c4 = (tid & 7) * 4;
    float4 v = *(const float4*)&W[(size_t)(k0 + r) * Nc + n0 + c4];
    tile[r][c4 + 0] = v.x; tile[r][c4 + 1] = v.y;
    tile[r][c4 + 2] = v.z; tile[r][c4 + 3] = v.w;
    __syncthreads();
    ushort4 o;
    o.x = f2bf(tile[c4 + 0][r]); o.y = f2bf(tile[c4 + 1][r]);
    o.z = f2bf(tile[c4 + 2][r]); o.w = f2bf(tile[c4 + 3][r]);
    *(ushort4*)&Wt[(size_t)(n0 + r) * K + k0 + c4] = o;
}

// ---------------- layernorm; ADD3 fuses hin = h + x0 + se ----------------
template<bool ADD3, typename OutT>
__global__ __launch_bounds__(256) void ln_kernel(
    const float* __restrict__ src, const float* __restrict__ x0,
    const float* __restrict__ se, const float* __restrict__ w,
    float* __restrict__ hin_out, OutT* __restrict__ out)
{
    int row = blockIdx.x;
    size_t base = (size_t)row * NN;
    int tid = threadIdx.x;
    float v[3];
    float s = 0.f, ss = 0.f;
#pragma unroll
    for (int i = 0; i < 3; ++i) {
        int c = tid + i * 256;
        float val = src[base + c];
        if (ADD3) { val += x0[base + c] + se[c]; hin_out[base + c] = val; }
        v[i] = val; s += val; ss += val * val;
    }
#pragma unroll
    for (int off = 32; off; off >>= 1) { s += __shfl_xor(s, off); ss += __shfl_xor(ss, off); }
    __shared__ float rs[4], rss[4], bc[2];
    int wid = tid >> 6, lane = tid & 63;
    if (lane == 0) { rs[wid] = s; rss[wid] = ss; }
    __syncthreads();
    if (tid == 0) {
        float S  = rs[0] + rs[1] + rs[2] + rs[3];
        float SS = rss[0] + rss[1] + rss[2] + rss[3];
        float mu = S / (float)NN;
        float var = SS / (float)NN - mu * mu;
        bc[0] = mu; bc[1] = rsqrtf(var + 1e-5f);
    }
    __syncthreads();
    float mu = bc[0], rsig = bc[1];
#pragma unroll
    for (int i = 0; i < 3; ++i) {
        int c = tid + i * 256;
        float o = (v[i] - mu) * rsig * w[c];
        if constexpr (sizeof(OutT) == 2) out[base + c] = (OutT)f2bf(o);
        else out[base + c] = o;
    }
}

// ---------------- bf16 MFMA GEMM: C[M,N] = A[M,K] @ Bt[N,K]^T (+epilogue) ----------------
template<int EPI, typename OutT>
__global__ __launch_bounds__(256) void mgemm(
    const unsigned short* __restrict__ A, const unsigned short* __restrict__ Bt,
    const float* __restrict__ res, OutT* __restrict__ C, int N, int K)
{
    __shared__ unsigned short Asb[128 * 32];
    __shared__ unsigned short Bsb[128 * 32];
    int tid = threadIdx.x;
    int row0 = blockIdx.y * 128, col0 = blockIdx.x * 128;
    const unsigned short* Ap = A + (size_t)row0 * K;
    const unsigned short* Bp = Bt + (size_t)col0 * K;
    int lane = tid & 63, wid = tid >> 6;
    int wr = wid >> 1, wc = wid & 1;
    int fr = lane & 15, fq = lane >> 4;

    f32x4 acc[4][4];
#pragma unroll
    for (int m = 0; m < 4; ++m)
#pragma unroll
        for (int n = 0; n < 4; ++n)
#pragma unroll
            for (int r = 0; r < 4; ++r) acc[m][n][r] = 0.f;

    int ldso = (tid & 192) * 8;

    for (int k0 = 0; k0 < K; k0 += 32) {
        __syncthreads();
#pragma unroll
        for (int i = 0; i < 2; ++i) {
            int c = i * 256 + tid;
            __builtin_amdgcn_global_load_lds(
                (const __attribute__((address_space(1))) void*)(Ap + (size_t)(c >> 2) * K + k0 + (c & 3) * 8),
                (__attribute__((address_space(3))) void*)(Asb + i * 2048 + ldso), 16, 0, 0);
            __builtin_amdgcn_global_load_lds(
                (const __attribute__((address_space(1))) void*)(Bp + (size_t)(c >> 2) * K + k0 + (c & 3) * 8),
                (__attribute__((address_space(3))) void*)(Bsb + i * 2048 + ldso), 16, 0, 0);
        }
        __syncthreads();
        const unsigned short* Ab = Asb + (wr * 64 + fr) * 32 + fq * 8;
        const unsigned short* Bb = Bsb + (wc * 64 + fr) * 32 + fq * 8;
        bf16x8 af[4], bfr[4];
#pragma unroll
        for (int m = 0; m < 4; ++m) af[m] = *(const bf16x8*)(Ab + m * 512);
#pragma unroll
        for (int n = 0; n < 4; ++n) bfr[n] = *(const bf16x8*)(Bb + n * 512);
#pragma unroll
        for (int m = 0; m < 4; ++m)
#pragma unroll
            for (int n = 0; n < 4; ++n)
                acc[m][n] = __builtin_amdgcn_mfma_f32_16x16x32_bf16(af[m], bfr[n], acc[m][n], 0, 0, 0);
    }

#pragma unroll
    for (int m = 0; m < 4; ++m) {
#pragma unroll
        for (int n = 0; n < 4; ++n) {
            int col = col0 + wc * 64 + n * 16 + fr;
#pragma unroll
            for (int r = 0; r < 4; ++r) {
                int row = row0 + wr * 64 + m * 16 + fq * 4 + r;
                float v = acc[m][n][r];
                if (EPI == 1) v = 0.5f * v * (1.0f + erff(v * 0.70710678118654752f));
                if (EPI == 2) v += res[(size_t)row * N + col];
                if constexpr (sizeof(OutT) == 2) C[(size_t)row * N + col] = (OutT)f2bf(v);
                else C[(size_t)row * N + col] = v;
            }
        }
    }
}

// ---------------- flash MFMA attention ----------------
// grid (T/64, H, B), 256 thr = 4 waves; wave w owns q-rows [qt*64+w*16, +16), all 64 d.
// Per KV tile of 64 keys: stage K row-major + V transposed in LDS (stride 72),
// S = mfma(Q, K) -> online softmax in-register -> P via LDS -> O += mfma(P, Vt).
__global__ __launch_bounds__(256) void fattn_kernel(const unsigned short* __restrict__ qkv,
                                                    unsigned short* __restrict__ y)
{
    int qt = blockIdx.x, h = blockIdx.y, b = blockIdx.z;
    int tid = threadIdx.x, lane = tid & 63, w = tid >> 6;
    int fr = lane & 15, fq = lane >> 4;

    __shared__ unsigned short Ks[64 * 72];
    __shared__ unsigned short Vts[64 * 72];
    __shared__ unsigned short Ps[64 * 72];

    // Q fragments in registers for the whole kernel
    int qrow = qt * 64 + w * 16 + fr;                 // A-frag: row = lane&15
    const unsigned short* qp = qkv + (size_t)(b * TT + qrow) * 2304 + h * 64 + fq * 8;
    bf16x8 qf0 = *(const bf16x8*)qp;
    bf16x8 qf1 = *(const bf16x8*)(qp + 32);

    f32x4 acco[4];
#pragma unroll
    for (int n = 0; n < 4; ++n)
#pragma unroll
        for (int r = 0; r < 4; ++r) acco[n][r] = 0.f;
    float mrow[4] = {-1e30f, -1e30f, -1e30f, -1e30f};
    float lrow[4] = {0.f, 0.f, 0.f, 0.f};

    for (int kt = 0; kt <= qt; ++kt) {
        __syncthreads();
        { // stage K (row-major) and V (transposed), stride 72
            int r = tid >> 2, c0 = (tid & 3) * 16;
            const us8* kp = (const us8*)&qkv[(size_t)(b * TT + kt * 64 + r) * 2304 + 768 + h * 64 + c0];
            us8 k0 = kp[0], k1 = kp[1];
            *(us8*)&Ks[r * 72 + c0] = k0;
            *(us8*)&Ks[r * 72 + c0 + 8] = k1;
            const us8* vp = (const us8*)&qkv[(size_t)(b * TT + kt * 64 + r) * 2304 + 1536 + h * 64 + c0];
            us8 v0 = vp[0], v1 = vp[1];
#pragma unroll
            for (int i = 0; i < 8; ++i) {
                Vts[(c0 + i) * 72 + r] = v0[i];
                Vts[(c0 + 8 + i) * 72 + r] = v1[i];
            }
        }
        __syncthreads();

        // S = Q K^T  (acc layout: row q = fq*4+r, col j = n*16+fr)
        f32x4 accs[4];
#pragma unroll
        for (int n = 0; n < 4; ++n) {
#pragma unroll
            for (int r = 0; r < 4; ++r) accs[n][r] = 0.f;
            bf16x8 kf0 = *(const bf16x8*)&Ks[(n * 16 + fr) * 72 + fq * 8];
            bf16x8 kf1 = *(const bf16x8*)&Ks[(n * 16 + fr) * 72 + 32 + fq * 8];
            accs[n] = __builtin_amdgcn_mfma_f32_16x16x32_bf16(qf0, kf0, accs[n], 0, 0, 0);
            accs[n] = __builtin_amdgcn_mfma_f32_16x16x32_bf16(qf1, kf1, accs[n], 0, 0, 0);
        }

        // scale + causal mask (only diagonal tile has masked entries)
        bool diag = (kt == qt);
#pragma unroll
        for (int n = 0; n < 4; ++n) {
            int j = kt * 64 + n * 16 + fr;
#pragma unroll
            for (int r = 0; r < 4; ++r) {
                float s = accs[n][r] * 0.125f;
                if (diag) { int q = qt * 64 + w * 16 + fq * 4 + r; if (j > q) s = -1e30f; }
                accs[n][r] = s;
            }
        }

        // online softmax: per q-row (fixed fq,r) reduce across fr lanes
        float rmax[4], psum[4];
#pragma unroll
        for (int r = 0; r < 4; ++r) {
            float m = fmaxf(fmaxf(accs[0][r], accs[1][r]), fmaxf(accs[2][r], accs[3][r]));
#pragma unroll
            for (int off = 8; off; off >>= 1) m = fmaxf(m, __shfl_xor(m, off));
            rmax[r] = m;
        }
        float fac[4];
#pragma unroll
        for (int r = 0; r < 4; ++r) {
            float mn = fmaxf(mrow[r], rmax[r]);
            fac[r] = __expf(mrow[r] - mn);
            mrow[r] = mn;
            psum[r] = 0.f;
        }
#pragma unroll
        for (int n = 0; n < 4; ++n)
#pragma unroll
            for (int r = 0; r < 4; ++r) {
                float p = __expf(accs[n][r] - mrow[r]);
                accs[n][r] = p;
                psum[r] += p;
            }
#pragma unroll
        for (int r = 0; r < 4; ++r) {
#pragma unroll
            for (int off = 8; off; off >>= 1) psum[r] += __shfl_xor(psum[r], off);
            lrow[r] = lrow[r] * fac[r] + psum[r];
        }

        // write P to LDS (bf16) in wave-private rows, rescale O
#pragma unroll
        for (int n = 0; n < 4; ++n)
#pragma unroll
            for (int r = 0; r < 4; ++r)
                Ps[(w * 16 + fq * 4 + r) * 72 + n * 16 + fr] = f2bf(accs[n][r]);
#pragma unroll
        for (int n = 0; n < 4; ++n)
#pragma unroll
            for (int r = 0; r < 4; ++r) acco[n][r] *= fac[r];

        // PV: O += P @ V   (A-frag from Ps rows, B-frag from Vt rows)
        bf16x8 pf0 = *(const bf16x8*)&Ps[(w * 16 + fr) * 72 + fq * 8];
        bf16x8 pf1 = *(const bf16x8*)&Ps[(w * 16 + fr) * 72 + 32 + fq * 8];
#pragma unroll
        for (int n = 0; n < 4; ++n) {
            bf16x8 vf0 = *(const bf16x8*)&Vts[(n * 16 + fr) * 72 + fq * 8];
            bf16x8 vf1 = *(const bf16x8*)&Vts[(n * 16 + fr) * 72 + 32 + fq * 8];
            acco[n] = __builtin_amdgcn_mfma_f32_16x16x32_bf16(pf0, vf0, acco[n], 0, 0, 0);
            acco[n] = __builtin_amdgcn_mfma_f32_16x16x32_bf16(pf1, vf1, acco[n], 0, 0, 0);
        }
    }

    // epilogue: O / l -> y
#pragma unroll
    for (int r = 0; r < 4; ++r) {
        int qout = qt * 64 + w * 16 + fq * 4 + r;
        float inv = 1.0f / lrow[r];
        unsigned short* yp = y + (size_t)(b * TT + qout) * NN + h * 64;
#pragma unroll
        for (int n = 0; n < 4; ++n)
            yp[n * 16 + fr] = f2bf(acco[n][r] * inv);
    }
}

// ---------------- logits ----------------
__global__ __launch_bounds__(256) void logits_kernel(const float* __restrict__ hf,
                                                     const float* __restrict__ wte,
                                                     float* __restrict__ out)
{
    __shared__ float hl[BB][NN];
    for (int i = threadIdx.x; i < BB * NN; i += 256) {
        int b = i / NN, d = i % NN;
        hl[b][d] = hf[(size_t)(b * TT + TT - 1) * NN + d];
    }
    __syncthreads();
    int w = threadIdx.x >> 6, lane = threadIdx.x & 63;
    int v = blockIdx.x * 4 + w;
    if (v >= VV) return;
    float acc[BB] = {};
    const float* wr = wte + (size_t)v * NN;
    for (int d = lane; d < NN; d += 64) {
        float wv = wr[d];
#pragma unroll
        for (int b = 0; b < BB; ++b) acc[b] += wv * hl[b][d];
    }
#pragma unroll
    for (int off = 32; off; off >>= 1)
#pragma unroll
        for (int b = 0; b < BB; ++b) acc[b] += __shfl_xor(acc[b], off);
    if (lane == 0)
#pragma unroll
        for (int b = 0; b < BB; ++b) out[(size_t)b * VV + v] = acc[b];
}

extern "C" void kernel_launch(void* const* d_in, const int* in_sizes, int n_in,
                              void* d_out, int out_size, void* d_ws, size_t ws_size,
                              hipStream_t stream) {
    const int*   idx       = (const int*)d_in[0];
    const float* wte       = (const float*)d_in[1];
    const float* wpe       = (const float*)d_in[2];
    const float* step_emb  = (const float*)d_in[3];
    const float* ln1_w     = (const float*)d_in[4];
    const float* ln2_w     = (const float*)d_in[5];
    const float* lnf_w     = (const float*)d_in[6];
    const float* c_attn    = (const float*)d_in[7];
    const float* attn_proj = (const float*)d_in[8];
    const float* c_fc      = (const float*)d_in[9];
    const float* mlp_proj  = (const float*)d_in[10];
    float* out = (float*)d_out;

    float* ws = (float*)d_ws;
    const size_t RC = (size_t)MM * NN;
    float* x0  = ws;
    float* h   = ws + RC;
    float* hin = ws + 2 * RC;
    unsigned short* big = (unsigned short*)(ws + 3 * RC);
    unsigned short* lnb = (unsigned short*)(ws + 3 * RC + (size_t)MM * 3072 / 2);
    unsigned short* yb       = lnb + RC;
    unsigned short* cattn_bt = yb + RC;
    unsigned short* aproj_bt = cattn_bt + (size_t)2304 * 768;
    unsigned short* cfc_bt   = aproj_bt + (size_t)768 * 768;
    unsigned short* mproj_bt = cfc_bt + (size_t)768 * 3072;

    wconv_kernel<<<dim3(2304 / 32, 768 / 32), 256, 0, stream>>>(c_attn, cattn_bt, 768, 2304);
    wconv_kernel<<<dim3(768 / 32, 768 / 32), 256, 0, stream>>>(attn_proj, aproj_bt, 768, 768);
    wconv_kernel<<<dim3(3072 / 32, 768 / 32), 256, 0, stream>>>(c_fc, cfc_bt, 768, 3072);
    wconv_kernel<<<dim3(768 / 32, 3072 / 32), 256, 0, stream>>>(mlp_proj, mproj_bt, 3072, 768);

    embed_kernel<<<MM, 256, 0, stream>>>(idx, wte, wpe, x0, h);

    for (int l = 0; l < LL; ++l) {
        ln_kernel<true, unsigned short><<<MM, 256, 0, stream>>>(h, x0, step_emb + l * NN, ln1_w, hin, lnb);
        mgemm<0, unsigned short><<<dim3(2304 / 128, MM / 128), 256, 0, stream>>>(lnb, cattn_bt, nullptr, big, 2304, 768);
        fattn_kernel<<<dim3(TT / 64, HH, BB), 256, 0, stream>>>(big, yb);
        mgemm<2, float><<<dim3(768 / 128, MM / 128), 256, 0, stream>>>(yb, aproj_bt, hin, hin, 768, 768);
        ln_kernel<false, unsigned short><<<MM, 256, 0, stream>>>(hin, nullptr, nullptr, ln2_w, nullptr, lnb);
        mgemm<1, unsigned short><<<dim3(3072 / 128, MM / 128), 256, 0, stream>>>(lnb, cfc_bt, nullptr, big, 3072, 768);
        mgemm<2, float><<<dim3(768 / 128, MM / 128), 256, 0, stream>>>(big, mproj_bt, hin, h, 768, 3072);
    }

    ln_kernel<false, float><<<MM, 256, 0, stream>>>(h, nullptr, nullptr, lnf_w, nullptr, x0);
    logits_kernel<<<(VV + 3) / 4, 256, 0, stream>>>(x0, wte, out);
}

// Round 4
// 2403.490 us; speedup vs baseline: 5.1523x; 1.0752x over previous
//
#include <hip/hip_runtime.h>
#include <hip/hip_bf16.h>
#include <math.h>

#define BB 8
#define TT 512
#define VV 50257
#define NN 768
#define HH 12
#define LL 12
#define MM (BB*TT)   // 4096 rows

typedef short bf16x8 __attribute__((ext_vector_type(8)));
typedef float f32x4 __attribute__((ext_vector_type(4)));
typedef unsigned short us8 __attribute__((ext_vector_type(8)));

__device__ __forceinline__ float bf2f(unsigned short u) {
    union { unsigned int i; float f; } x; x.i = ((unsigned int)u) << 16; return x.f;
}
__device__ __forceinline__ unsigned short f2bf(float f) {
    union { __hip_bfloat16 h; unsigned short u; } c; c.h = __float2bfloat16(f); return c.u;
}

// ---------------- embedding: x0 = wte[idx] + wpe ; h = x0 ----------------
__global__ void embed_kernel(const int* __restrict__ idx, const float* __restrict__ wte,
                             const float* __restrict__ wpe, float* __restrict__ x0,
                             float* __restrict__ h)
{
    int row = blockIdx.x;
    int t = row % TT;
    int tok = idx[row];
    const float* wt = wte + (size_t)tok * NN;
    const float* wp = wpe + (size_t)t * NN;
    float* px = x0 + (size_t)row * NN;
    float* ph = h  + (size_t)row * NN;
    for (int c = threadIdx.x; c < NN; c += blockDim.x) {
        float v = wt[c] + wp[c];
        px[c] = v; ph[c] = v;
    }
}

// ---------------- weight convert+transpose: W[K][Nc] fp32 -> Wt[Nc][K] bf16 ----------------
__global__ __launch_bounds__(256) void wconv_kernel(const float* __restrict__ W,
                                                    unsigned short* __restrict__ Wt,
                                                    int K, int Nc)
{
    __shared__ float tile[32][33];
    int n0 = blockIdx.x * 32, k0 = blockIdx.y * 32;
    int tid = threadIdx.x;
    int r = tid >> 3, c4 = (tid & 7) * 4;
    float4 v = *(const float4*)&W[(size_t)(k0 + r) * Nc + n0 + c4];
    tile[r][c4 + 0] = v.x; tile[r][c4 + 1] = v.y;
    tile[r][c4 + 2] = v.z; tile[r][c4 + 3] = v.w;
    __syncthreads();
    ushort4 o;
    o.x = f2bf(tile[c4 + 0][r]); o.y = f2bf(tile[c4 + 1][r]);
    o.z = f2bf(tile[c4 + 2][r]); o.w = f2bf(tile[c4 + 3][r]);
    *(ushort4*)&Wt[(size_t)(n0 + r) * K + k0 + c4] = o;
}

// ---------------- layernorm; ADD3 fuses hin = h + x0 + se ----------------
template<bool ADD3, typename OutT>
__global__ __launch_bounds__(256) void ln_kernel(
    const float* __restrict__ src, const float* __restrict__ x0,
    const float* __restrict__ se, const float* __restrict__ w,
    float* __restrict__ hin_out, OutT* __restrict__ out)
{
    int row = blockIdx.x;
    size_t base = (size_t)row * NN;
    int tid = threadIdx.x;
    float v[3];
    float s = 0.f, ss = 0.f;
#pragma unroll
    for (int i = 0; i < 3; ++i) {
        int c = tid + i * 256;
        float val = src[base + c];
        if (ADD3) { val += x0[base + c] + se[c]; hin_out[base + c] = val; }
        v[i] = val; s += val; ss += val * val;
    }
#pragma unroll
    for (int off = 32; off; off >>= 1) { s += __shfl_xor(s, off); ss += __shfl_xor(ss, off); }
    __shared__ float rs[4], rss[4], bc[2];
    int wid = tid >> 6, lane = tid & 63;
    if (lane == 0) { rs[wid] = s; rss[wid] = ss; }
    __syncthreads();
    if (tid == 0) {
        float S  = rs[0] + rs[1] + rs[2] + rs[3];
        float SS = rss[0] + rss[1] + rss[2] + rss[3];
        float mu = S / (float)NN;
        float var = SS / (float)NN - mu * mu;
        bc[0] = mu; bc[1] = rsqrtf(var + 1e-5f);
    }
    __syncthreads();
    float mu = bc[0], rsig = bc[1];
#pragma unroll
    for (int i = 0; i < 3; ++i) {
        int c = tid + i * 256;
        float o = (v[i] - mu) * rsig * w[c];
        if constexpr (sizeof(OutT) == 2) out[base + c] = (OutT)f2bf(o);
        else out[base + c] = o;
    }
}

// ---------------- bf16 MFMA GEMM, 2-phase double-buffered ----------------
// C[M,N] = A[M,K] @ Bt[N,K]^T ; EPI: 0 none, 1 exact GELU, 2 residual add
template<int EPI, typename OutT>
__global__ __launch_bounds__(256) void mgemm(
    const unsigned short* __restrict__ A, const unsigned short* __restrict__ Bt,
    const float* __restrict__ res, OutT* __restrict__ C, int N, int K)
{
    __shared__ unsigned short Asb[2][128 * 32];
    __shared__ unsigned short Bsb[2][128 * 32];
    int tid = threadIdx.x;
    int row0 = blockIdx.y * 128, col0 = blockIdx.x * 128;
    const unsigned short* Ap = A + (size_t)row0 * K;
    const unsigned short* Bp = Bt + (size_t)col0 * K;
    int lane = tid & 63, wid = tid >> 6;
    int wr = wid >> 1, wc = wid & 1;
    int fr = lane & 15, fq = lane >> 4;

    f32x4 acc[4][4];
#pragma unroll
    for (int m = 0; m < 4; ++m)
#pragma unroll
        for (int n = 0; n < 4; ++n)
#pragma unroll
            for (int r = 0; r < 4; ++r) acc[m][n][r] = 0.f;

    int ldso = (tid & 192) * 8;   // wave-uniform LDS base (elems); HW adds lane*16B

    auto STAGE = [&](int buf, int k0) {
#pragma unroll
        for (int i = 0; i < 2; ++i) {
            int c = i * 256 + tid;              // row = c>>2, 16B piece = c&3
            __builtin_amdgcn_global_load_lds(
                (const __attribute__((address_space(1))) void*)(Ap + (size_t)(c >> 2) * K + k0 + (c & 3) * 8),
                (__attribute__((address_space(3))) void*)(Asb[buf] + i * 2048 + ldso), 16, 0, 0);
            __builtin_amdgcn_global_load_lds(
                (const __attribute__((address_space(1))) void*)(Bp + (size_t)(c >> 2) * K + k0 + (c & 3) * 8),
                (__attribute__((address_space(3))) void*)(Bsb[buf] + i * 2048 + ldso), 16, 0, 0);
        }
    };

    int NT = K / 32;
    STAGE(0, 0);
    asm volatile("s_waitcnt vmcnt(0)" ::: "memory");
    __syncthreads();

    int cur = 0;
    for (int t = 0; t < NT; ++t) {
        if (t + 1 < NT) STAGE(cur ^ 1, (t + 1) * 32);   // prefetch overlaps compute below
        const unsigned short* Ab = Asb[cur] + (wr * 64 + fr) * 32 + fq * 8;
        const unsigned short* Bb = Bsb[cur] + (wc * 64 + fr) * 32 + fq * 8;
        bf16x8 af[4], bfr[4];
#pragma unroll
        for (int m = 0; m < 4; ++m) af[m] = *(const bf16x8*)(Ab + m * 512);
#pragma unroll
        for (int n = 0; n < 4; ++n) bfr[n] = *(const bf16x8*)(Bb + n * 512);
#pragma unroll
        for (int m = 0; m < 4; ++m)
#pragma unroll
            for (int n = 0; n < 4; ++n)
                acc[m][n] = __builtin_amdgcn_mfma_f32_16x16x32_bf16(af[m], bfr[n], acc[m][n], 0, 0, 0);
        asm volatile("s_waitcnt vmcnt(0)" ::: "memory");
        __syncthreads();
        cur ^= 1;
    }

#pragma unroll
    for (int m = 0; m < 4; ++m) {
#pragma unroll
        for (int n = 0; n < 4; ++n) {
            int col = col0 + wc * 64 + n * 16 + fr;
#pragma unroll
            for (int r = 0; r < 4; ++r) {
                int row = row0 + wr * 64 + m * 16 + fq * 4 + r;
                float v = acc[m][n][r];
                if (EPI == 1) v = 0.5f * v * (1.0f + erff(v * 0.70710678118654752f));
                if (EPI == 2) v += res[(size_t)row * N + col];
                if constexpr (sizeof(OutT) == 2) C[(size_t)row * N + col] = (OutT)f2bf(v);
                else C[(size_t)row * N + col] = v;
            }
        }
    }
}

// ---------------- flash MFMA attention ----------------
__global__ __launch_bounds__(256) void fattn_kernel(const unsigned short* __restrict__ qkv,
                                                    unsigned short* __restrict__ y)
{
    int qt = blockIdx.x, h = blockIdx.y, b = blockIdx.z;
    int tid = threadIdx.x, lane = tid & 63, w = tid >> 6;
    int fr = lane & 15, fq = lane >> 4;

    __shared__ unsigned short Ks[64 * 72];
    __shared__ unsigned short Vts[64 * 72];
    __shared__ unsigned short Ps[64 * 72];

    int qrow = qt * 64 + w * 16 + fr;
    const unsigned short* qp = qkv + (size_t)(b * TT + qrow) * 2304 + h * 64 + fq * 8;
    bf16x8 qf0 = *(const bf16x8*)qp;
    bf16x8 qf1 = *(const bf16x8*)(qp + 32);

    f32x4 acco[4];
#pragma unroll
    for (int n = 0; n < 4; ++n)
#pragma unroll
        for (int r = 0; r < 4; ++r) acco[n][r] = 0.f;
    float mrow[4] = {-1e30f, -1e30f, -1e30f, -1e30f};
    float lrow[4] = {0.f, 0.f, 0.f, 0.f};

    for (int kt = 0; kt <= qt; ++kt) {
        __syncthreads();
        {
            int r = tid >> 2, c0 = (tid & 3) * 16;
            const us8* kp = (const us8*)&qkv[(size_t)(b * TT + kt * 64 + r) * 2304 + 768 + h * 64 + c0];
            us8 k0 = kp[0], k1 = kp[1];
            *(us8*)&Ks[r * 72 + c0] = k0;
            *(us8*)&Ks[r * 72 + c0 + 8] = k1;
            const us8* vp = (const us8*)&qkv[(size_t)(b * TT + kt * 64 + r) * 2304 + 1536 + h * 64 + c0];
            us8 v0 = vp[0], v1 = vp[1];
#pragma unroll
            for (int i = 0; i < 8; ++i) {
                Vts[(c0 + i) * 72 + r] = v0[i];
                Vts[(c0 + 8 + i) * 72 + r] = v1[i];
            }
        }
        __syncthreads();

        f32x4 accs[4];
#pragma unroll
        for (int n = 0; n < 4; ++n) {
#pragma unroll
            for (int r = 0; r < 4; ++r) accs[n][r] = 0.f;
            bf16x8 kf0 = *(const bf16x8*)&Ks[(n * 16 + fr) * 72 + fq * 8];
            bf16x8 kf1 = *(const bf16x8*)&Ks[(n * 16 + fr) * 72 + 32 + fq * 8];
            accs[n] = __builtin_amdgcn_mfma_f32_16x16x32_bf16(qf0, kf0, accs[n], 0, 0, 0);
            accs[n] = __builtin_amdgcn_mfma_f32_16x16x32_bf16(qf1, kf1, accs[n], 0, 0, 0);
        }

        bool diag = (kt == qt);
#pragma unroll
        for (int n = 0; n < 4; ++n) {
            int j = kt * 64 + n * 16 + fr;
#pragma unroll
            for (int r = 0; r < 4; ++r) {
                float s = accs[n][r] * 0.125f;
                if (diag) { int q = qt * 64 + w * 16 + fq * 4 + r; if (j > q) s = -1e30f; }
                accs[n][r] = s;
            }
        }

        float rmax[4], psum[4];
#pragma unroll
        for (int r = 0; r < 4; ++r) {
            float m = fmaxf(fmaxf(accs[0][r], accs[1][r]), fmaxf(accs[2][r], accs[3][r]));
#pragma unroll
            for (int off = 8; off; off >>= 1) m = fmaxf(m, __shfl_xor(m, off));
            rmax[r] = m;
        }
        float fac[4];
#pragma unroll
        for (int r = 0; r < 4; ++r) {
            float mn = fmaxf(mrow[r], rmax[r]);
            fac[r] = __expf(mrow[r] - mn);
            mrow[r] = mn;
            psum[r] = 0.f;
        }
#pragma unroll
        for (int n = 0; n < 4; ++n)
#pragma unroll
            for (int r = 0; r < 4; ++r) {
                float p = __expf(accs[n][r] - mrow[r]);
                accs[n][r] = p;
                psum[r] += p;
            }
#pragma unroll
        for (int r = 0; r < 4; ++r) {
#pragma unroll
            for (int off = 8; off; off >>= 1) psum[r] += __shfl_xor(psum[r], off);
            lrow[r] = lrow[r] * fac[r] + psum[r];
        }

#pragma unroll
        for (int n = 0; n < 4; ++n)
#pragma unroll
            for (int r = 0; r < 4; ++r)
                Ps[(w * 16 + fq * 4 + r) * 72 + n * 16 + fr] = f2bf(accs[n][r]);
#pragma unroll
        for (int n = 0; n < 4; ++n)
#pragma unroll
            for (int r = 0; r < 4; ++r) acco[n][r] *= fac[r];

        bf16x8 pf0 = *(const bf16x8*)&Ps[(w * 16 + fr) * 72 + fq * 8];
        bf16x8 pf1 = *(const bf16x8*)&Ps[(w * 16 + fr) * 72 + 32 + fq * 8];
#pragma unroll
        for (int n = 0; n < 4; ++n) {
            bf16x8 vf0 = *(const bf16x8*)&Vts[(n * 16 + fr) * 72 + fq * 8];
            bf16x8 vf1 = *(const bf16x8*)&Vts[(n * 16 + fr) * 72 + 32 + fq * 8];
            acco[n] = __builtin_amdgcn_mfma_f32_16x16x32_bf16(pf0, vf0, acco[n], 0, 0, 0);
            acco[n] = __builtin_amdgcn_mfma_f32_16x16x32_bf16(pf1, vf1, acco[n], 0, 0, 0);
        }
    }

#pragma unroll
    for (int r = 0; r < 4; ++r) {
        int qout = qt * 64 + w * 16 + fq * 4 + r;
        float inv = 1.0f / lrow[r];
        unsigned short* yp = y + (size_t)(b * TT + qout) * NN + h * 64;
#pragma unroll
        for (int n = 0; n < 4; ++n)
            yp[n * 16 + fr] = f2bf(acco[n][r] * inv);
    }
}

// ---------------- logits: out[b,v] = dot(hf[b,T-1,:], wte[v,:]) ----------------
// grid-stride; 4 vocab rows per wave per chunk; float4 loads; butterfly reduce
__global__ __launch_bounds__(256) void logits_kernel(const float* __restrict__ hf,
                                                     const float* __restrict__ wte,
                                                     float* __restrict__ out)
{
    __shared__ float hl[BB][NN];
    for (int i = threadIdx.x; i < BB * NN / 4; i += 256) {
        int b = i / (NN / 4), c = i % (NN / 4);
        ((float4*)&hl[b][0])[c] = ((const float4*)(hf + (size_t)(b * TT + TT - 1) * NN))[c];
    }
    __syncthreads();
    int w = threadIdx.x >> 6, lane = threadIdx.x & 63;
    const int NCH = (VV + 3) / 4;   // 12565 chunks of 4 rows

    for (int cid = blockIdx.x * 4 + w; cid < NCH; cid += gridDim.x * 4) {
        int v0 = cid * 4;
        float4 wv[4][3];
#pragma unroll
        for (int r = 0; r < 4; ++r) {
            int v = min(v0 + r, VV - 1);
            const float4* wr4 = (const float4*)(wte + (size_t)v * NN);
#pragma unroll
            for (int i = 0; i < 3; ++i) wv[r][i] = wr4[i * 64 + lane];
        }
        float acc[4][BB];
#pragma unroll
        for (int r = 0; r < 4; ++r)
#pragma unroll
            for (int b = 0; b < BB; ++b) acc[r][b] = 0.f;
#pragma unroll
        for (int i = 0; i < 3; ++i) {
#pragma unroll
            for (int b = 0; b < BB; ++b) {
                float4 h4 = *(const float4*)&hl[b][i * 256 + lane * 4];
#pragma unroll
                for (int r = 0; r < 4; ++r)
                    acc[r][b] += wv[r][i].x * h4.x + wv[r][i].y * h4.y
                               + wv[r][i].z * h4.z + wv[r][i].w * h4.w;
            }
        }
#pragma unroll
        for (int off = 32; off; off >>= 1)
#pragma unroll
            for (int r = 0; r < 4; ++r)
#pragma unroll
                for (int b = 0; b < BB; ++b) acc[r][b] += __shfl_xor(acc[r][b], off);
        if (lane == 0) {
#pragma unroll
            for (int r = 0; r < 4; ++r) {
                int v = v0 + r;
                if (v < VV)
#pragma unroll
                    for (int b = 0; b < BB; ++b) out[(size_t)b * VV + v] = acc[r][b];
            }
        }
    }
}

extern "C" void kernel_launch(void* const* d_in, const int* in_sizes, int n_in,
                              void* d_out, int out_size, void* d_ws, size_t ws_size,
                              hipStream_t stream) {
    const int*   idx       = (const int*)d_in[0];
    const float* wte       = (const float*)d_in[1];
    const float* wpe       = (const float*)d_in[2];
    const float* step_emb  = (const float*)d_in[3];
    const float* ln1_w     = (const float*)d_in[4];
    const float* ln2_w     = (const float*)d_in[5];
    const float* lnf_w     = (const float*)d_in[6];
    const float* c_attn    = (const float*)d_in[7];
    const float* attn_proj = (const float*)d_in[8];
    const float* c_fc      = (const float*)d_in[9];
    const float* mlp_proj  = (const float*)d_in[10];
    float* out = (float*)d_out;

    float* ws = (float*)d_ws;
    const size_t RC = (size_t)MM * NN;
    float* x0  = ws;
    float* h   = ws + RC;
    float* hin = ws + 2 * RC;
    unsigned short* big = (unsigned short*)(ws + 3 * RC);
    unsigned short* lnb = (unsigned short*)(ws + 3 * RC + (size_t)MM * 3072 / 2);
    unsigned short* yb       = lnb + RC;
    unsigned short* cattn_bt = yb + RC;
    unsigned short* aproj_bt = cattn_bt + (size_t)2304 * 768;
    unsigned short* cfc_bt   = aproj_bt + (size_t)768 * 768;
    unsigned short* mproj_bt = cfc_bt + (size_t)768 * 3072;

    wconv_kernel<<<dim3(2304 / 32, 768 / 32), 256, 0, stream>>>(c_attn, cattn_bt, 768, 2304);
    wconv_kernel<<<dim3(768 / 32, 768 / 32), 256, 0, stream>>>(attn_proj, aproj_bt, 768, 768);
    wconv_kernel<<<dim3(3072 / 32, 768 / 32), 256, 0, stream>>>(c_fc, cfc_bt, 768, 3072);
    wconv_kernel<<<dim3(768 / 32, 3072 / 32), 256, 0, stream>>>(mlp_proj, mproj_bt, 3072, 768);

    embed_kernel<<<MM, 256, 0, stream>>>(idx, wte, wpe, x0, h);

    for (int l = 0; l < LL; ++l) {
        ln_kernel<true, unsigned short><<<MM, 256, 0, stream>>>(h, x0, step_emb + l * NN, ln1_w, hin, lnb);
        mgemm<0, unsigned short><<<dim3(2304 / 128, MM / 128), 256, 0, stream>>>(lnb, cattn_bt, nullptr, big, 2304, 768);
        fattn_kernel<<<dim3(TT / 64, HH, BB), 256, 0, stream>>>(big, yb);
        mgemm<2, float><<<dim3(768 / 128, MM / 128), 256, 0, stream>>>(yb, aproj_bt, hin, hin, 768, 768);
        ln_kernel<false, unsigned short><<<MM, 256, 0, stream>>>(hin, nullptr, nullptr, ln2_w, nullptr, lnb);
        mgemm<1, unsigned short><<<dim3(3072 / 128, MM / 128), 256, 0, stream>>>(lnb, cfc_bt, nullptr, big, 3072, 768);
        mgemm<2, float><<<dim3(768 / 128, MM / 128), 256, 0, stream>>>(big, mproj_bt, hin, h, 768, 3072);
    }

    ln_kernel<false, float><<<MM, 256, 0, stream>>>(h, nullptr, nullptr, lnf_w, nullptr, x0);
    logits_kernel<<<1024, 256, 0, stream>>>(x0, wte, out);
}